// Round 1
// baseline (26.855 us; speedup 1.0000x reference)
//
#include <hip/hip_runtime.h>

// StyleLossDiag: x [16,512,64,64] f32, target [8192] f32 -> scalar f32.
// g[row] = sum(x[row,:]^2) / 2^25 ; loss = mean((g - target)^2).
// Memory-bound streaming reduction: 134 MB read, ~21 us at 6.3 TB/s.

#define ROWS   8192
#define ROWLEN 4096
// 16*512*64*64 = 2^25 -> multiply by exact power-of-two reciprocal
#define INV_NORM (1.0f / 33554432.0f)

__global__ __launch_bounds__(256) void rowdiag_kernel(
    const float* __restrict__ x,
    const float* __restrict__ target,
    float* __restrict__ ws)
{
    const int row = blockIdx.x;
    const float4* xr = reinterpret_cast<const float4*>(x) + (size_t)row * (ROWLEN / 4);

    // 256 threads * 4 float4 = 4096 elements, fully coalesced
    float s = 0.0f;
#pragma unroll
    for (int i = 0; i < 4; ++i) {
        float4 v = xr[threadIdx.x + i * 256];
        s += v.x * v.x + v.y * v.y + v.z * v.z + v.w * v.w;
    }

    // wave (64-lane) butterfly reduce
#pragma unroll
    for (int off = 32; off > 0; off >>= 1)
        s += __shfl_down(s, off, 64);

    __shared__ float lds[4];
    const int lane = threadIdx.x & 63;
    const int wave = threadIdx.x >> 6;
    if (lane == 0) lds[wave] = s;
    __syncthreads();

    if (threadIdx.x == 0) {
        float tot = (lds[0] + lds[1]) + (lds[2] + lds[3]);
        float d = tot * INV_NORM - target[row];
        ws[row] = d * d;
    }
}

__global__ __launch_bounds__(256) void final_reduce_kernel(
    const float* __restrict__ ws,
    float* __restrict__ out)
{
    float s = 0.0f;
#pragma unroll
    for (int i = 0; i < ROWS / 256; ++i)
        s += ws[threadIdx.x + i * 256];

#pragma unroll
    for (int off = 32; off > 0; off >>= 1)
        s += __shfl_down(s, off, 64);

    __shared__ float lds[4];
    const int lane = threadIdx.x & 63;
    const int wave = threadIdx.x >> 6;
    if (lane == 0) lds[wave] = s;
    __syncthreads();

    if (threadIdx.x == 0)
        out[0] = ((lds[0] + lds[1]) + (lds[2] + lds[3])) * (1.0f / (float)ROWS);
}

extern "C" void kernel_launch(void* const* d_in, const int* in_sizes, int n_in,
                              void* d_out, int out_size, void* d_ws, size_t ws_size,
                              hipStream_t stream)
{
    const float* x      = (const float*)d_in[0];   // [16,512,64,64]
    const float* target = (const float*)d_in[1];   // [8192]
    float* out = (float*)d_out;                    // [1]
    float* ws  = (float*)d_ws;                     // >= 8192 floats

    rowdiag_kernel<<<ROWS, 256, 0, stream>>>(x, target, ws);
    final_reduce_kernel<<<1, 256, 0, stream>>>(ws, out);
}